// Round 1
// baseline (471.409 us; speedup 1.0000x reference)
//
#include <hip/hip_runtime.h>

// Encoder: 4-layer MLP (3->16->32->64->128) + mean-pool over 2M points.
// Algebraic simplification: layer 4 is linear (no relu) and mean is linear:
//   mean_n(relu_h3[n] @ W4^T + b4) == mean_n(relu_h3[n]) @ W4^T + b4
// so we only compute L1/L2/L3 per point (2608 MACs) and pool the 64-vector.
//
// Compute-bound on f32 VALU (10.4 GFLOP @ 157 TF ~ 66 us ideal).
// Weights are read with wave-uniform indices -> compiler emits s_load /
// SGPR-operand v_fma (no LDS pipe pressure, no per-lane weight traffic).
// All layer loops fully unrolled so h1/h2/acc stay in registers.

#define GRID1 768   // 3 blocks/CU x 256 CUs, matches __launch_bounds__(256,3)

__global__ __launch_bounds__(256, 3)
void mlp_partial_kernel(const float* __restrict__ pts, int npts,
                        const float* __restrict__ W1, const float* __restrict__ b1,
                        const float* __restrict__ W2, const float* __restrict__ b2,
                        const float* __restrict__ W3, const float* __restrict__ b3,
                        float* __restrict__ partials)
{
    float acc[64];
#pragma unroll
    for (int j = 0; j < 64; ++j) acc[j] = 0.0f;

    const int nth = gridDim.x * blockDim.x;
    for (int i = blockIdx.x * blockDim.x + threadIdx.x; i < npts; i += nth) {
        const float x0 = pts[3 * i + 0];
        const float x1 = pts[3 * i + 1];
        const float x2 = pts[3 * i + 2];

        float h1[16];
#pragma unroll
        for (int j = 0; j < 16; ++j) {
            float s = fmaf(x2, W1[3 * j + 2],
                      fmaf(x1, W1[3 * j + 1],
                      fmaf(x0, W1[3 * j + 0], b1[j])));
            h1[j] = fmaxf(s, 0.0f);
        }

        float h2[32];
#pragma unroll
        for (int j = 0; j < 32; ++j) {
            float s0 = b2[j], s1 = 0.0f;   // 2 chains -> hide 4-cyc FMA latency
#pragma unroll
            for (int k = 0; k < 16; k += 2) {
                s0 = fmaf(h1[k],     W2[16 * j + k],     s0);
                s1 = fmaf(h1[k + 1], W2[16 * j + k + 1], s1);
            }
            h2[j] = fmaxf(s0 + s1, 0.0f);
        }

#pragma unroll
        for (int j = 0; j < 64; ++j) {
            float s0 = b3[j], s1 = 0.0f;
#pragma unroll
            for (int k = 0; k < 32; k += 2) {
                s0 = fmaf(h2[k],     W3[32 * j + k],     s0);
                s1 = fmaf(h2[k + 1], W3[32 * j + k + 1], s1);
            }
            acc[j] += fmaxf(s0 + s1, 0.0f);
        }
    }

    // 64-lane butterfly reduce of each acc[j] (once per thread lifetime)
#pragma unroll
    for (int j = 0; j < 64; ++j) {
        float v = acc[j];
        v += __shfl_xor(v, 1);
        v += __shfl_xor(v, 2);
        v += __shfl_xor(v, 4);
        v += __shfl_xor(v, 8);
        v += __shfl_xor(v, 16);
        v += __shfl_xor(v, 32);
        acc[j] = v;
    }

    __shared__ float red[4][64];
    const int lane = threadIdx.x & 63;
    const int wave = threadIdx.x >> 6;
    if (lane == 0) {
#pragma unroll
        for (int j = 0; j < 64; ++j) red[wave][j] = acc[j];
    }
    __syncthreads();
    if (threadIdx.x < 64) {
        const int j = threadIdx.x;
        partials[(size_t)blockIdx.x * 64 + j] =
            red[0][j] + red[1][j] + red[2][j] + red[3][j];
    }
}

// Sum the per-block partials, divide by N, apply the (linear) layer 4.
__global__ __launch_bounds__(256)
void finalize_kernel(const float* __restrict__ partials, int nblocks, float inv_n,
                     const float* __restrict__ W4, const float* __restrict__ b4,
                     float* __restrict__ out)
{
    __shared__ float colsum[4][64];
    __shared__ float meanv[64];
    const int t = threadIdx.x;          // 256 threads, 1 block
    const int j = t & 63, part = t >> 6;

    float s = 0.0f;
    for (int b = part; b < nblocks; b += 4) s += partials[(size_t)b * 64 + j];
    colsum[part][j] = s;
    __syncthreads();

    if (t < 64)
        meanv[t] = (colsum[0][t] + colsum[1][t] + colsum[2][t] + colsum[3][t]) * inv_n;
    __syncthreads();

    if (t < 128) {
        float s0 = b4[t], s1 = 0.0f;
#pragma unroll
        for (int k = 0; k < 64; k += 2) {
            s0 = fmaf(W4[64 * t + k],     meanv[k],     s0);
            s1 = fmaf(W4[64 * t + k + 1], meanv[k + 1], s1);
        }
        out[t] = s0 + s1;
    }
}

extern "C" void kernel_launch(void* const* d_in, const int* in_sizes, int n_in,
                              void* d_out, int out_size, void* d_ws, size_t ws_size,
                              hipStream_t stream)
{
    const float* pts = (const float*)d_in[0];
    const float* W1  = (const float*)d_in[1];
    const float* b1  = (const float*)d_in[2];
    const float* W2  = (const float*)d_in[3];
    const float* b2  = (const float*)d_in[4];
    const float* W3  = (const float*)d_in[5];
    const float* b3  = (const float*)d_in[6];
    const float* W4  = (const float*)d_in[7];
    const float* b4  = (const float*)d_in[8];

    const int npts = in_sizes[0] / 3;     // 2,000,000
    float* partials = (float*)d_ws;       // GRID1 x 64 floats (fully overwritten)

    mlp_partial_kernel<<<GRID1, 256, 0, stream>>>(pts, npts, W1, b1, W2, b2, W3, b3, partials);
    finalize_kernel<<<1, 256, 0, stream>>>(partials, GRID1, 1.0f / (float)npts,
                                           W4, b4, (float*)d_out);
}

// Round 2
// 448.428 us; speedup vs baseline: 1.0512x; 1.0512x over previous
//
#include <hip/hip_runtime.h>

// Encoder: 4-layer MLP (3->16->32->64->128) + mean-pool over 2M points.
// Layer 4 is linear and mean is linear => apply W4/b4 AFTER pooling:
//   mean_n(relu_h3[n] @ W4^T + b4) == mean_n(relu_h3[n]) @ W4^T + b4
// Per-point work: L1+L2+L3 = 2608 MACs; f32-VALU roofline ~74 us.
//
// Round-1 lesson: __launch_bounds__(256,3) capped VGPRs at 170 and the
// compiler spilled acc[64]+h2[32] (VGPR_Count=84, 43 MB scratch writes,
// VALUBusy 65%). Fix: cap at 256 VGPRs (2 waves/SIMD) so all state is
// register-resident. Weights are wave-uniform -> scalar-pipe s_loads,
// no LDS pressure.

#define GRID1 512   // 2 blocks/CU x 256 CUs, matches __launch_bounds__(256,2)

__global__ __launch_bounds__(256, 2)
void mlp_partial_kernel(const float* __restrict__ pts, int npts,
                        const float* __restrict__ W1, const float* __restrict__ b1,
                        const float* __restrict__ W2, const float* __restrict__ b2,
                        const float* __restrict__ W3, const float* __restrict__ b3,
                        float* __restrict__ partials)
{
    float acc[64];
#pragma unroll
    for (int j = 0; j < 64; ++j) acc[j] = 0.0f;

    const int nth = gridDim.x * blockDim.x;
    for (int i = blockIdx.x * blockDim.x + threadIdx.x; i < npts; i += nth) {
        const float x0 = pts[3 * i + 0];
        const float x1 = pts[3 * i + 1];
        const float x2 = pts[3 * i + 2];

        float h1[16];
#pragma unroll
        for (int j = 0; j < 16; ++j) {
            float s = fmaf(x2, W1[3 * j + 2],
                      fmaf(x1, W1[3 * j + 1],
                      fmaf(x0, W1[3 * j + 0], b1[j])));
            h1[j] = fmaxf(s, 0.0f);
        }

        float h2[32];
#pragma unroll
        for (int j = 0; j < 32; ++j) {
            float s0 = b2[j], s1 = 0.0f;   // 2 chains hide 4-cyc FMA latency
#pragma unroll
            for (int k = 0; k < 16; k += 2) {
                s0 = fmaf(h1[k],     W2[16 * j + k],     s0);
                s1 = fmaf(h1[k + 1], W2[16 * j + k + 1], s1);
            }
            h2[j] = fmaxf(s0 + s1, 0.0f);
        }

#pragma unroll
        for (int j = 0; j < 64; ++j) {
            float s0 = b3[j], s1 = 0.0f;
#pragma unroll
            for (int k = 0; k < 32; k += 2) {
                s0 = fmaf(h2[k],     W3[32 * j + k],     s0);
                s1 = fmaf(h2[k + 1], W3[32 * j + k + 1], s1);
            }
            acc[j] += fmaxf(s0 + s1, 0.0f);
        }
    }

    // 64-lane butterfly reduce of each acc[j] (once per thread lifetime)
#pragma unroll
    for (int j = 0; j < 64; ++j) {
        float v = acc[j];
        v += __shfl_xor(v, 1);
        v += __shfl_xor(v, 2);
        v += __shfl_xor(v, 4);
        v += __shfl_xor(v, 8);
        v += __shfl_xor(v, 16);
        v += __shfl_xor(v, 32);
        acc[j] = v;
    }

    __shared__ float red[4][64];
    const int lane = threadIdx.x & 63;
    const int wave = threadIdx.x >> 6;
    if (lane == 0) {
#pragma unroll
        for (int j = 0; j < 64; ++j) red[wave][j] = acc[j];
    }
    __syncthreads();
    if (threadIdx.x < 64) {
        const int j = threadIdx.x;
        partials[(size_t)blockIdx.x * 64 + j] =
            red[0][j] + red[1][j] + red[2][j] + red[3][j];
    }
}

// Sum the per-block partials, divide by N, apply the (linear) layer 4.
__global__ __launch_bounds__(256)
void finalize_kernel(const float* __restrict__ partials, int nblocks, float inv_n,
                     const float* __restrict__ W4, const float* __restrict__ b4,
                     float* __restrict__ out)
{
    __shared__ float colsum[4][64];
    __shared__ float meanv[64];
    const int t = threadIdx.x;          // 256 threads, 1 block
    const int j = t & 63, part = t >> 6;

    float s = 0.0f;
    for (int b = part; b < nblocks; b += 4) s += partials[(size_t)b * 64 + j];
    colsum[part][j] = s;
    __syncthreads();

    if (t < 64)
        meanv[t] = (colsum[0][t] + colsum[1][t] + colsum[2][t] + colsum[3][t]) * inv_n;
    __syncthreads();

    if (t < 128) {
        float s0 = b4[t], s1 = 0.0f;
#pragma unroll
        for (int k = 0; k < 64; k += 2) {
            s0 = fmaf(W4[64 * t + k],     meanv[k],     s0);
            s1 = fmaf(W4[64 * t + k + 1], meanv[k + 1], s1);
        }
        out[t] = s0 + s1;
    }
}

extern "C" void kernel_launch(void* const* d_in, const int* in_sizes, int n_in,
                              void* d_out, int out_size, void* d_ws, size_t ws_size,
                              hipStream_t stream)
{
    const float* pts = (const float*)d_in[0];
    const float* W1  = (const float*)d_in[1];
    const float* b1  = (const float*)d_in[2];
    const float* W2  = (const float*)d_in[3];
    const float* b2  = (const float*)d_in[4];
    const float* W3  = (const float*)d_in[5];
    const float* b3  = (const float*)d_in[6];
    const float* W4  = (const float*)d_in[7];
    const float* b4  = (const float*)d_in[8];

    const int npts = in_sizes[0] / 3;     // 2,000,000
    float* partials = (float*)d_ws;       // GRID1 x 64 floats (fully overwritten)

    mlp_partial_kernel<<<GRID1, 256, 0, stream>>>(pts, npts, W1, b1, W2, b2, W3, b3, partials);
    finalize_kernel<<<1, 256, 0, stream>>>(partials, GRID1, 1.0f / (float)npts,
                                           W4, b4, (float*)d_out);
}